// Round 6
// baseline (496.222 us; speedup 1.0000x reference)
//
#include <hip/hip_runtime.h>

// EdgeEmbedding: out[i,:] = ete[data[i],:] + segsum(attr_table[flat_attr_ids], attr_seg_ids)[data[i],:]
// N=1e6, D=256, NUM_TYPES=1000, TOTAL_ATTRS=50k, ATTR_NUM=200k. All f32, idx int32.

#define EE_D4  64          // float4s per row
#define EE_NT  1000
#define EE_K   4           // types per build block

typedef float fvec4 __attribute__((ext_vector_type(4)));

// ---------- shared: build comb[t] = ete[t] + segsum(attr)[t]  (proven R4 kernel) ----------
__global__ __launch_bounds__(256) void ee_build_comb(
        const fvec4* __restrict__ ete,
        const fvec4* __restrict__ attr,
        const int* __restrict__ ids,
        const int* __restrict__ segs,
        fvec4* __restrict__ comb, int na) {
    const int t0   = blockIdx.x * EE_K;
    const int tid  = threadIdx.x;
    const int wave = tid >> 6;
    const int lane = tid & 63;

    fvec4 acc[EE_K];
    #pragma unroll
    for (int k = 0; k < EE_K; ++k) acc[k] = (fvec4)0.f;

    for (int base = wave * 64; base < na; base += 256) {
        int a = base + lane;
        int s = -1, id = 0;
        if (a < na) { s = segs[a]; id = ids[a]; }
        #pragma unroll
        for (int k = 0; k < EE_K; ++k) {
            unsigned long long m = __ballot(s == t0 + k);
            while (m) {
                int j = __ffsll((long long)m) - 1;
                m &= m - 1;
                int aid = __shfl(id, j);
                acc[k] += attr[(size_t)aid * EE_D4 + lane];
            }
        }
    }

    __shared__ fvec4 red[EE_K][4][64];
    #pragma unroll
    for (int k = 0; k < EE_K; ++k) red[k][wave][lane] = acc[k];
    __syncthreads();
    if (wave < EE_K) {
        int k = wave;
        fvec4 r = red[k][0][lane];
        #pragma unroll
        for (int w = 1; w < 4; ++w) r += red[k][w][lane];
        r += ete[(size_t)(t0 + k) * EE_D4 + lane];
        comb[(size_t)(t0 + k) * EE_D4 + lane] = r;
    }
}

// ---------- bucketed path ----------
__global__ void ee_zero(int* __restrict__ p, int n) {
    int i = blockIdx.x * blockDim.x + threadIdx.x;
    if (i < n) p[i] = 0;
}

__global__ __launch_bounds__(256) void ee_hist(const int* __restrict__ data, int n,
                                               int* __restrict__ hist) {
    __shared__ int lh[EE_NT];
    for (int i = threadIdx.x; i < EE_NT; i += 256) lh[i] = 0;
    __syncthreads();
    for (int r = blockIdx.x * blockDim.x + threadIdx.x; r < n; r += gridDim.x * blockDim.x)
        atomicAdd(&lh[data[r]], 1);
    __syncthreads();
    for (int i = threadIdx.x; i < EE_NT; i += 256) {
        int c = lh[i];
        if (c) atomicAdd(&hist[i], c);
    }
}

// exclusive scan of hist[0..999] -> start[0..1000] (start[1000] = total)
__global__ __launch_bounds__(1024) void ee_scan(const int* __restrict__ hist,
                                                int* __restrict__ start) {
    __shared__ int a[1024], b[1024];
    int tid = threadIdx.x;
    a[tid] = (tid < EE_NT) ? hist[tid] : 0;
    __syncthreads();
    int* src = a; int* dst = b;
    #pragma unroll
    for (int off = 1; off < 1024; off <<= 1) {
        int v = src[tid];
        if (tid >= off) v += src[tid - off];
        dst[tid] = v;
        __syncthreads();
        int* t = src; src = dst; dst = t;
    }
    if (tid <= EE_NT) start[tid] = (tid == 0) ? 0 : src[tid - 1];
}

__global__ __launch_bounds__(256) void ee_scatter_ids(const int* __restrict__ data, int n,
        const int* __restrict__ start, int* __restrict__ cursor, int* __restrict__ rowlist) {
    for (int r = blockIdx.x * blockDim.x + threadIdx.x; r < n; r += gridDim.x * blockDim.x) {
        int t = data[r];
        int pos = atomicAdd(&cursor[t], 1);
        rowlist[start[t] + pos] = r;
    }
}

// One block per type: comb[t] row held in registers; pure NT-store stream.
__global__ __launch_bounds__(256) void ee_scatter_out(const fvec4* __restrict__ comb,
        const int* __restrict__ start, const int* __restrict__ rowlist,
        fvec4* __restrict__ out) {
    const int t    = blockIdx.x;
    const int wave = threadIdx.x >> 6;
    const int lane = threadIdx.x & 63;
    const int s = start[t], e = start[t + 1];
    const fvec4 v = comb[(size_t)t * EE_D4 + lane];   // row in regs for the whole block

    for (int base = s + wave * 64; base < e; base += 256) {
        int i = base + lane;
        int rid = (i < e) ? rowlist[i] : 0;           // coalesced 256B rowid load
        int lim = e - base;
        if (lim >= 64) {
            #pragma unroll                            // j compile-time -> v_readlane
            for (int j = 0; j < 64; ++j) {
                int r = __builtin_amdgcn_readlane(rid, j);
                __builtin_nontemporal_store(v, &out[(size_t)r * EE_D4 + lane]);
            }
        } else {
            for (int j = 0; j < lim; ++j) {
                int r = __shfl(rid, j);
                __builtin_nontemporal_store(v, &out[(size_t)r * EE_D4 + lane]);
            }
        }
    }
}

// ---------- fallback gather (proven R4, 256 us) ----------
__global__ __launch_bounds__(256) void ee_gather_out(
        const int* __restrict__ data,
        const fvec4* __restrict__ comb,
        fvec4* __restrict__ out, int n) {
    const int gid  = blockIdx.x * blockDim.x + threadIdx.x;
    const int wave = gid >> 6;
    const int lane = gid & 63;
    const int nw   = (gridDim.x * blockDim.x) >> 6;

    for (int base = wave * 64; base < n; base += nw * 64) {
        int r = base + lane;
        int idx = (r < n) ? __builtin_nontemporal_load(&data[r]) : 0;
        int lim = n - base;
        if (lim >= 64) {
            #pragma unroll
            for (int j = 0; j < 64; ++j) {
                int t = __builtin_amdgcn_readlane(idx, j);
                fvec4 v = comb[(size_t)t * EE_D4 + lane];
                __builtin_nontemporal_store(v, &out[(size_t)(base + j) * EE_D4 + lane]);
            }
        } else {
            for (int j = 0; j < lim; ++j) {
                int t = __shfl(idx, j);
                fvec4 v = comb[(size_t)t * EE_D4 + lane];
                __builtin_nontemporal_store(v, &out[(size_t)(base + j) * EE_D4 + lane]);
            }
        }
    }
}

extern "C" void kernel_launch(void* const* d_in, const int* in_sizes, int n_in,
                              void* d_out, int out_size, void* d_ws, size_t ws_size,
                              hipStream_t stream) {
    const int*   data          = (const int*)d_in[0];
    const float* attr_table    = (const float*)d_in[1];
    const float* ete           = (const float*)d_in[2];
    const int*   flat_attr_ids = (const int*)d_in[3];
    const int*   attr_seg_ids  = (const int*)d_in[4];
    int N  = in_sizes[0];   // 1,000,000 edges
    int TA = in_sizes[3];   // 50,000 ragged attrs

    // ws layout: comb (1 MB) | hist (4 KB) | cursor (4 KB) | start (4 KB) | rowlist (4 MB)
    char* ws = (char*)d_ws;
    fvec4* comb    = (fvec4*)ws;
    int*   hist    = (int*)(ws + (1 << 20));
    int*   cursor  = hist + 1024;
    int*   start   = cursor + 1024;
    int*   rowlist = start + 1024;
    size_t need = (1 << 20) + 3 * 4096 + (size_t)N * 4;

    ee_build_comb<<<EE_NT / EE_K, 256, 0, stream>>>(
        (const fvec4*)ete, (const fvec4*)attr_table,
        flat_attr_ids, attr_seg_ids, comb, TA);

    if (ws_size >= need) {
        ee_zero<<<8, 256, 0, stream>>>(hist, 2048);            // hist + cursor
        ee_hist<<<128, 256, 0, stream>>>(data, N, hist);
        ee_scan<<<1, 1024, 0, stream>>>(hist, start);
        ee_scatter_ids<<<1024, 256, 0, stream>>>(data, N, start, cursor, rowlist);
        ee_scatter_out<<<EE_NT, 256, 0, stream>>>(comb, start, rowlist, (fvec4*)d_out);
    } else {
        ee_gather_out<<<2048, 256, 0, stream>>>(data, comb, (fvec4*)d_out, N);
    }
}

// Round 7
// 261.851 us; speedup vs baseline: 1.8951x; 1.8951x over previous
//
#include <hip/hip_runtime.h>

// EdgeEmbedding: out[i,:] = ete[data[i],:] + segsum(attr_table[flat_attr_ids], attr_seg_ids)[data[i],:]
// N=1e6, D=256, NUM_TYPES=1000, TOTAL_ATTRS=50k, ATTR_NUM=200k. f32 in/out, idx int32.
// R7: comb table stored as bf16 (RNE) -> halves the per-row L2 read stream.
// Store stream (1 KB NT sequential), index path (readlane), launch config: unchanged from R4.

#define EE_D4  64          // float4s per output row
#define EE_NT  1000
#define EE_K   4           // types per build block

typedef float        fvec4 __attribute__((ext_vector_type(4)));
typedef unsigned int uvec2 __attribute__((ext_vector_type(2)));

__device__ __forceinline__ unsigned int ee_pack_bf16(float a, float b) {
    unsigned int ua = __builtin_bit_cast(unsigned int, a);
    unsigned int ub = __builtin_bit_cast(unsigned int, b);
    ua = (ua + 0x7FFFu + ((ua >> 16) & 1u)) >> 16;   // RNE
    ub = (ub + 0x7FFFu + ((ub >> 16) & 1u)) >> 16;
    return ua | (ub << 16);
}

// Phase A: build comb[t] = ete[t] + segsum(attr)[t], stored bf16.
// One block per EE_K types; 4 waves scan (seg,id) with coalesced loads + ballot.
__global__ __launch_bounds__(256) void ee_build_comb(
        const fvec4* __restrict__ ete,
        const fvec4* __restrict__ attr,
        const int* __restrict__ ids,
        const int* __restrict__ segs,
        uvec2* __restrict__ comb, int na) {   // comb: [1000][64] x 8B (bf16 row = 512B)
    const int t0   = blockIdx.x * EE_K;
    const int tid  = threadIdx.x;
    const int wave = tid >> 6;
    const int lane = tid & 63;

    fvec4 acc[EE_K];
    #pragma unroll
    for (int k = 0; k < EE_K; ++k) acc[k] = (fvec4)0.f;

    for (int base = wave * 64; base < na; base += 256) {
        int a = base + lane;
        int s = -1, id = 0;
        if (a < na) { s = segs[a]; id = ids[a]; }
        #pragma unroll
        for (int k = 0; k < EE_K; ++k) {
            unsigned long long m = __ballot(s == t0 + k);
            while (m) {
                int j = __ffsll((long long)m) - 1;
                m &= m - 1;
                int aid = __shfl(id, j);
                acc[k] += attr[(size_t)aid * EE_D4 + lane];
            }
        }
    }

    __shared__ fvec4 red[EE_K][4][64];
    #pragma unroll
    for (int k = 0; k < EE_K; ++k) red[k][wave][lane] = acc[k];
    __syncthreads();
    if (wave < EE_K) {
        int k = wave;
        fvec4 r = red[k][0][lane];
        #pragma unroll
        for (int w = 1; w < 4; ++w) r += red[k][w][lane];
        r += ete[(size_t)(t0 + k) * EE_D4 + lane];
        uvec2 p;
        p.x = ee_pack_bf16(r.x, r.y);
        p.y = ee_pack_bf16(r.z, r.w);
        comb[(size_t)(t0 + k) * EE_D4 + lane] = p;
    }
}

__device__ __forceinline__ fvec4 ee_unpack(uvec2 q) {
    fvec4 v;
    v.x = __builtin_bit_cast(float, q.x << 16);
    v.y = __builtin_bit_cast(float, q.x & 0xFFFF0000u);
    v.z = __builtin_bit_cast(float, q.y << 16);
    v.w = __builtin_bit_cast(float, q.y & 0xFFFF0000u);
    return v;
}

// Phase B: out[r][:] = unpack(comb[data[r]][:]). Each wave: one coalesced NT load
// of 64 indices, then 64 unrolled (readlane -> 8B L2 load -> unpack -> 1KB NT store).
__global__ __launch_bounds__(256) void ee_gather_out(
        const int* __restrict__ data,
        const uvec2* __restrict__ comb,
        fvec4* __restrict__ out, int n) {
    const int gid  = blockIdx.x * blockDim.x + threadIdx.x;
    const int wave = gid >> 6;
    const int lane = gid & 63;
    const int nw   = (gridDim.x * blockDim.x) >> 6;

    for (int base = wave * 64; base < n; base += nw * 64) {
        int r = base + lane;
        int idx = (r < n) ? __builtin_nontemporal_load(&data[r]) : 0;
        int lim = n - base;
        if (lim >= 64) {
            #pragma unroll                               // j compile-time -> v_readlane
            for (int j = 0; j < 64; ++j) {
                int t = __builtin_amdgcn_readlane(idx, j);
                uvec2 q = comb[(size_t)t * EE_D4 + lane];
                __builtin_nontemporal_store(ee_unpack(q), &out[(size_t)(base + j) * EE_D4 + lane]);
            }
        } else {
            for (int j = 0; j < lim; ++j) {
                int t = __shfl(idx, j);
                uvec2 q = comb[(size_t)t * EE_D4 + lane];
                __builtin_nontemporal_store(ee_unpack(q), &out[(size_t)(base + j) * EE_D4 + lane]);
            }
        }
    }
}

extern "C" void kernel_launch(void* const* d_in, const int* in_sizes, int n_in,
                              void* d_out, int out_size, void* d_ws, size_t ws_size,
                              hipStream_t stream) {
    const int*   data          = (const int*)d_in[0];
    const float* attr_table    = (const float*)d_in[1];
    const float* ete           = (const float*)d_in[2];
    const int*   flat_attr_ids = (const int*)d_in[3];
    const int*   attr_seg_ids  = (const int*)d_in[4];
    uvec2* comb = (uvec2*)d_ws;                    // 1000*64*8B = 512 KB scratch
    int N  = in_sizes[0];                          // 1,000,000 edges
    int TA = in_sizes[3];                          // 50,000 ragged attrs

    ee_build_comb<<<EE_NT / EE_K, 256, 0, stream>>>(
        (const fvec4*)ete, (const fvec4*)attr_table,
        flat_attr_ids, attr_seg_ids, comb, TA);

    ee_gather_out<<<2048, 256, 0, stream>>>(
        data, comb, (fvec4*)d_out, N);
}